// Round 12
// baseline (3652.457 us; speedup 1.0000x reference)
//
#include <hip/hip_runtime.h>
#include <hip/hip_bf16.h>

// LSTM: B=64, D=32, H=512, T=1024. gates = [h,x] @ [W_hh;W_ih]^T + b_ih + b_hh
// Round 25: R19 base (validated 2905us steady: 64 blocks = 4 groups x 16
// slices, 512 thr, 8 waves, lane-local swapped-MFMA epilogue, sc0sc1
// data-as-flag 4B words, tag bit16 ring-2, hs dbuf) + REPRESENTATIVE
// LIGHT-POLL. Old poll: all 512 threads x 4 x 16B sc0sc1 per round = 2MB/
// round device-wide at the IC -> congestion inflates detect RTT. New detect:
// threads 0..127 each poll ONE 4B representative word (producer wave wg=tid,
// offset wg*256 -- published by that wave's lane 0 in the same instruction
// as all its other words), 64x less poll traffic; __syncthreads is the
// AND-join. Then one bulk load of all packets + R19 verify loop (every word
// self-tagged -> same-wave straggler words caught and retried; correctness
// and liveness invariants unchanged). Costs +1 RTT after detect, saves
// congestion during the whole detect window. LDS 80KB.

typedef unsigned short ushort_t;
typedef unsigned int   uint_t;
typedef unsigned long long u64_t;
typedef __attribute__((ext_vector_type(8))) short bf16x8;
typedef __attribute__((ext_vector_type(4))) float f32x4;
typedef __attribute__((ext_vector_type(4))) uint_t u32x4;

#define T_STEPS 1024
#define HID     512
#define KDIM    544   // 512 h + 32 x
#define NBLK    64    // 4 groups * 16 slices
#define NTHR    512

__device__ inline ushort_t f2bf(float x) {
    __hip_bfloat16 h = __float2bfloat16(x);
    return *(ushort_t*)&h;
}
__device__ inline float bf2f(ushort_t u) {
    __hip_bfloat16 h = *(__hip_bfloat16*)&u;
    return __bfloat162float(h);
}

__device__ inline f32x4 MFMA(bf16x8 a, bf16x8 b, f32x4 c) {
    return __builtin_amdgcn_mfma_f32_16x16x32_bf16(a, b, c, 0, 0, 0);
}

// coherent loads/stores (L1+L2 bypass, meet at Infinity Cache)
__device__ inline u32x4 cld16(const void* p) {
    u32x4 v;
    asm volatile("global_load_dwordx4 %0, %1, off sc0 sc1"
                 : "=v"(v) : "v"(p) : "memory");
    return v;
}
__device__ inline uint_t cld4(const void* p) {
    uint_t v;
    asm volatile("global_load_dword %0, %1, off sc0 sc1"
                 : "=v"(v) : "v"(p) : "memory");
    return v;
}
__device__ inline void cst4(void* p, uint_t v) {
    asm volatile("global_store_dword %0, %1, off sc0 sc1"
                 :: "v"(p), "v"(v) : "memory");
}
__device__ inline void waitvm0() {
    asm volatile("s_waitcnt vmcnt(0)" ::: "memory");
}

// is_tanh: tanh(v)=(1-e)/(1+e), e=2^(-2.885*v); sigmoid(v)=1/(1+e), e=2^(-1.4427*v)
__device__ inline float act_gate(float v, int is_tanh) {
    float vc = fminf(fmaxf(v, -43.f), 43.f);
    float kk = is_tanh ? -2.88539008f : -1.44269504f;
    float e  = __builtin_exp2f(vc * kk);
    float num = is_tanh ? (1.f - e) : 1.f;
    return num * __builtin_amdgcn_rcpf(1.f + e);
}

// ---------- prep kernels ----------

__global__ void k_init(uint_t* hx32) {
    int i = blockIdx.x * 256 + threadIdx.x;      // grid 256x256 = 65536
    // init h ring: value ~0 (denormal bf16), tag bit16 = 1 (differs from tag 0
    // expected at t=1/t=2) -> no ABA with init data.
    hx32[i] = 0x00010000u;                       // 2*4*128*16 x 16B = 65536 u32
}

__global__ void k_wcat(const float* __restrict__ wih, const float* __restrict__ whh,
                       ushort_t* __restrict__ wh, ushort_t* __restrict__ wl) {
    int r = blockIdx.x;                          // 2048 gate rows
    for (int k = threadIdx.x; k < KDIM; k += 256) {
        float w = (k < 512) ? whh[r * 512 + k] : wih[r * 32 + (k - 512)];
        ushort_t hh = f2bf(w);
        ushort_t ll = f2bf(w - bf2f(hh));
        wh[r * KDIM + k] = hh;
        wl[r * KDIM + k] = ll;
    }
}

// input (B=64, D=32, T=1024) fp32 -> xbuf[t][b][d] bf16 hi/lo
__global__ void k_xbuf(const float* __restrict__ in,
                       ushort_t* __restrict__ xh, ushort_t* __restrict__ xl) {
    __shared__ float tile[64][65];
    int bp = blockIdx.x >> 4;                    // batch pair 0..31
    int tt = blockIdx.x & 15;                    // t tile 0..15
    int t0 = tt * 64;
    int wv = threadIdx.x >> 6, l = threadIdx.x & 63;
    for (int r = wv * 16; r < wv * 16 + 16; r++) {
        int b = bp * 2 + (r >> 5), d = r & 31;
        tile[r][l] = in[(b * 32 + d) * 1024 + t0 + l];
    }
    __syncthreads();
    for (int i = 0; i < 16; i++) {
        int tl = wv * 16 + i;
        float v = tile[l][tl];
        ushort_t hh = f2bf(v);
        ushort_t ll = f2bf(v - bf2f(hh));
        int o = (t0 + tl) * 2048 + bp * 64 + l;  // = t*64*32 + b*32 + d
        xh[o] = hh;
        xl[o] = ll;
    }
}

// out[b][t] = conv_b + sum_s part[(g*16+s)*16 + bl][t]   (b = g*16+bl)
__global__ void k_reduce(const float* __restrict__ part, float* __restrict__ out,
                         const float* __restrict__ cvb) {
    int b = blockIdx.x >> 2;                     // 0..63
    int t = (blockIdx.x & 3) * 256 + threadIdx.x;
    int g = b >> 4, bl = b & 15;
    const float* p = part + ((size_t)(g * 16 * 16 + bl)) * 1024 + t;
    float sum = 0.f;
    #pragma unroll
    for (int s = 0; s < 16; s++) sum += p[(size_t)s * 16 * 1024];
    out[b * 1024 + t] = sum + cvb[0];
}

// ---------- main recurrent kernel ----------

__global__ __launch_bounds__(NTHR, 2) void k_lstm(
    const ushort_t* __restrict__ wh, const ushort_t* __restrict__ wlo,
    const ushort_t* __restrict__ xh, const ushort_t* __restrict__ xl,
    char* hx,
    const float* __restrict__ bih, const float* __restrict__ bhh,
    const float* __restrict__ convw, float* __restrict__ part)
{
    const int tid = threadIdx.x;
    const int w   = tid >> 6;          // wave 0..7
    const int l   = tid & 63;
    const int g   = blockIdx.x >> 4;   // batch group 0..3
    const int s   = blockIdx.x & 15;   // hidden slice 0..15 (32 units each)
    const int n   = l & 15;            // A-tile row (u-major: u=n>>2, gate=n&3)
    const int q   = l >> 4;            // quad (k-block; also: unit in epilogue)
    const int j   = s * 32 + w * 4 + q;// hidden unit owned in epilogue
    // weight row for the A-operand, tile rows ordered unit-major:
    // tile-row n -> global row = (n&3)*HID + s*32 + w*4 + (n>>2)
    const int roww = (n & 3) * HID + s * 32 + w * 4 + (n >> 2);
    const int b0  = g * 16;
    const int wg  = s * 8 + w;         // producing-wave id in group, 0..127

    __shared__ u64_t hs[2][4096];              // staged h, dbuf (64 KB)
    __shared__ float projsh[8][16][32];        // projection partials (16 KB)

    // W_hi AND W_lo fragments in registers: 17 K-chunks each (A-operand)
    bf16x8 Bh[17], Bl[17];
    #pragma unroll
    for (int c = 0; c < 17; c++) {
        Bh[c] = *(const bf16x8*)(wh  + roww * KDIM + c * 32 + q * 8);
        Bl[c] = *(const bf16x8*)(wlo + roww * KDIM + c * 32 + q * 8);
    }

    // epilogue constants: lane (q,n) owns unit j, batch n -> 4 gate biases
    float bias4[4];
    #pragma unroll
    for (int r = 0; r < 4; r++) bias4[r] = bih[r * HID + j] + bhh[r * HID + j];
    const float cw = convw[j];
    float cst = 0.f;                   // c-state: one (unit, batch) per lane

    // staging mapping: packet p = k*512+tid (k=0..3) -> wg' = p>>4, m = p&15
    // c = k*4 + (hi5>>3), sq = (hi5>>1)&3, sd = hi5&1
    const int m16 = tid & 15;
    const int hi5 = tid >> 4;
    const int sq  = (hi5 >> 1) & 3, sd = hi5 & 1, sc0v = hi5 >> 3;

    __syncthreads();

    union frag { u64_t d[2]; bf16x8 v; };

    for (int t = 0; t < T_STEPS; t++) {
        bf16x8 Ax, Lx;
        // x fragment (B-operand: lane (q,n) = x[batch n][dims q*8..+8])
        {
            int xo = (t * 64 + b0 + n) * 32 + q * 8;
            Ax = *(const bf16x8*)(xh + xo);
            Lx = *(const bf16x8*)(xl + xo);
        }

        const char* grpB = hx + (size_t)(((t & 1) * 4 + g)) * 32768;
        const char* srcB = grpB + tid * 16;

        // ---- detect: representative light-poll (threads 0..127 poll one
        //      4B word each = producer wave wg=tid's lane-0 word; barrier
        //      is the AND-join). 64x less IC traffic than all-thread poll.
        if (t > 0) {
            const uint_t exp = ((uint_t)(((t - 1) >> 1) & 1)) << 16;
            if (tid < 128) {
                const char* rp = grpB + tid * 256;
                for (;;) {
                    uint_t v = cld4(rp);
                    waitvm0();
                    if ((v & 0x10000u) == exp) break;
                    __builtin_amdgcn_s_sleep(2);
                }
            }
            __syncthreads();
        }

        // ---- bulk load + verify (expected to pass; same-wave straggler
        //      words are caught by the self-tags and retried) ----
        u32x4 hv[4];
        #pragma unroll
        for (int k = 0; k < 4; k++) hv[k] = cld16(srcB + k * 8192);
        waitvm0();
        if (t > 0) {
            const uint_t exp = ((uint_t)(((t - 1) >> 1) & 1)) << 16;
            for (;;) {
                bool ok = true;
                #pragma unroll
                for (int k = 0; k < 4; k++) {
                    if (((hv[k][0] & 0x10000u) != exp) ||
                        ((hv[k][1] & 0x10000u) != exp) ||
                        ((hv[k][2] & 0x10000u) != exp) ||
                        ((hv[k][3] & 0x10000u) != exp)) {
                        hv[k] = cld16(srcB + k * 8192);
                        ok = false;
                    }
                }
                if (ok) break;
                __builtin_amdgcn_s_sleep(1);
                waitvm0();
            }
        }
        // deinterleave dwords (hi,lo)x4 units -> hi x4, lo x4; into LDS dbuf
        {
            const int buf = t & 1;
            #pragma unroll
            for (int k = 0; k < 4; k++) {
                uint_t I0 = hv[k][0], I1 = hv[k][1];
                uint_t I2 = hv[k][2], I3 = hv[k][3];
                uint_t hA = __builtin_amdgcn_perm(I1, I0, 0x05040100u);
                uint_t hB = __builtin_amdgcn_perm(I3, I2, 0x05040100u);
                uint_t lA = __builtin_amdgcn_perm(I1, I0, 0x07060302u);
                uint_t lB = __builtin_amdgcn_perm(I3, I2, 0x07060302u);
                int c  = k * 4 + sc0v;
                int li = ((c * 4 + sq) * 16 + m16) * 2 + sd;
                hs[buf][li]        = (u64_t)hA | ((u64_t)hB << 32);
                hs[buf][li + 2048] = (u64_t)lA | ((u64_t)lB << 32);
            }
        }
        __syncthreads();   // the only other per-step barrier

        // fragments from LDS (B-operand; W in VGPRs as A-operand)
        const int buf = t & 1;
        f32x4 a0 = {0,0,0,0}, a1 = {0,0,0,0}, a2 = {0,0,0,0},
              a3 = {0,0,0,0}, a4 = {0,0,0,0}, a5 = {0,0,0,0};
        #pragma unroll
        for (int c = 0; c < 16; c++) {
            frag Ah, Al;
            int li = ((c * 4 + q) * 16 + n) * 2;
            Ah.v = *(const bf16x8*)&hs[buf][li];
            Al.v = *(const bf16x8*)&hs[buf][li + 2048];
            if (c & 1) {
                a1 = MFMA(Bh[c], Ah.v, a1);
                a3 = MFMA(Bl[c], Ah.v, a3);
                a5 = MFMA(Bh[c], Al.v, a5);
            } else {
                a0 = MFMA(Bh[c], Ah.v, a0);
                a2 = MFMA(Bl[c], Ah.v, a2);
                a4 = MFMA(Bh[c], Al.v, a4);
            }
        }
        {   // x chunk (c=16)
            a0 = MFMA(Bh[16], Ax, a0);
            a2 = MFMA(Bl[16], Ax, a2);
            a4 = MFMA(Bh[16], Lx, a4);
        }
        f32x4 D = (a0 + a1) + (a2 + a3) + (a4 + a5);

        // ---- lane-local epilogue: D[r] = gate r of (unit j, batch n) ----
        char* dstB = hx + (size_t)((((t + 1) & 1) * 4 + g) * 128 + wg) * 256;
        const uint_t tag32 = ((uint_t)((t >> 1) & 1)) << 16;
        float iv = act_gate(D[0] + bias4[0], 0);
        float fv = act_gate(D[1] + bias4[1], 0);
        float gv = act_gate(D[2] + bias4[2], 1);
        float ov = act_gate(D[3] + bias4[3], 0);
        float cc = fv * cst + iv * gv;
        cst = cc;
        float th = act_gate(cc, 1);
        float h  = ov * th;
        float pr = cw * h;
        {
            ushort_t hb = f2bf(h);
            uint_t hvp = (uint_t)hb;
            uint_t lvp = (uint_t)f2bf(h - bf2f(hb));
            uint_t word = (hvp | (lvp << 16)) & ~0x10000u;
            word |= tag32;                       // every word self-tagged
            // packet layout: wg*256 + batch*16 + unit*4 (identical to R13)
            cst4(dstB + n * 16 + q * 4, word);
        }
        // NO drain, NO flag: tagged data IS the publication.

        // projection partial (off critical path): sum over the wave's 4 units
        pr += __shfl_xor(pr, 16);
        pr += __shfl_xor(pr, 32);
        if (l < 16) projsh[w][l][t & 31] = pr;   // l==n when q==0
        if ((t & 31) == 31) {
            __syncthreads();
            // 512 entries (16 batches x 32 steps), one per thread
            int b = tid >> 5, tl = tid & 31;
            float v = ((projsh[0][b][tl] + projsh[1][b][tl]) +
                       (projsh[2][b][tl] + projsh[3][b][tl])) +
                      ((projsh[4][b][tl] + projsh[5][b][tl]) +
                       (projsh[6][b][tl] + projsh[7][b][tl]));
            float* dpt = part + (size_t)((g * 16 + s) * 16 + b) * 1024 + (t - 31);
            __builtin_nontemporal_store(v, dpt + tl);
            __syncthreads();
        }
    }
}

extern "C" void kernel_launch(void* const* d_in, const int* in_sizes, int n_in,
                              void* d_out, int out_size, void* d_ws, size_t ws_size,
                              hipStream_t stream) {
    const float* in  = (const float*)d_in[0];
    const float* Wih = (const float*)d_in[1];
    const float* Whh = (const float*)d_in[2];
    const float* bih = (const float*)d_in[3];
    const float* bhh = (const float*)d_in[4];
    const float* cvw = (const float*)d_in[5];
    const float* cvb = (const float*)d_in[6];
    float* out = (float*)d_out;

    char* ws = (char*)d_ws;
    ushort_t* wh  = (ushort_t*)ws; ws += (size_t)2048 * KDIM * 2;      // 2,228,224
    ushort_t* wl  = (ushort_t*)ws; ws += (size_t)2048 * KDIM * 2;
    ushort_t* xh  = (ushort_t*)ws; ws += (size_t)1024 * 64 * 32 * 2;   // 4,194,304
    ushort_t* xl  = (ushort_t*)ws; ws += (size_t)1024 * 64 * 32 * 2;
    char*     hx  = ws;            ws += (size_t)2 * 4 * 128 * 16 * 16;// 262,144
    float*    pp  = (float*)ws;    ws += (size_t)64 * 16 * 1024 * 4;   // 4,194,304
    // total ~17.3 MB of ws

    k_init<<<256, 256, 0, stream>>>((uint_t*)hx);
    k_wcat<<<2048, 256, 0, stream>>>(Wih, Whh, wh, wl);
    k_xbuf<<<512, 256, 0, stream>>>(in, xh, xl);
    k_lstm<<<NBLK, NTHR, 0, stream>>>(wh, wl, xh, xl, hx,
                                      bih, bhh, cvw, pp);
    k_reduce<<<256, 256, 0, stream>>>(pp, out, cvb);
}

// Round 13
// 2726.004 us; speedup vs baseline: 1.3399x; 1.3399x over previous
//
#include <hip/hip_runtime.h>
#include <hip/hip_bf16.h>

// LSTM: B=64, D=32, H=512, T=1024. gates = [h,x] @ [W_hh;W_ih]^T + b_ih + b_hh
// Round 26: R19 base (validated 2905us steady) MINUS the W_hi·h_lo correction
// plane. Budget re-audit: R19's compute phase was LDS-pipe-bound, not MFMA-
// bound -- 8 waves x 32 ds_read_b128/step = 256 b128 x ~12cy = 3072cy/CU/step
// (> MFMA 1980cy), explaining why every exchange-side lever was neutral.
// Dropping W_hi·h_lo removes the Al plane: 35 MFMAs/wave (was 51), ONE
// ds_read_b128 per chunk (was 2; LDS reads halve), staging perm+write
// halves, hs = 32KB (was 64KB). Kept: W_lo·h_hi (weight-truncation
// correction) and full x hi/lo. Packet format/tags/poll/epilogue BYTE-
// IDENTICAL to R19 (lo bits still transmitted, now unused -> zero protocol
// risk). Numerical delta: |W_hi·h_lo| ~ 2e-4 rms pre-activation; absmax
// expected ~6-10e-4 (was 4.88e-4). 64 blocks = 4 groups x 16 slices,
// 512 thr, 8 waves, lane-local epilogue, sc0sc1 data-as-flag 4B words,
// tag bit16 ring-2. LDS 48KB.

typedef unsigned short ushort_t;
typedef unsigned int   uint_t;
typedef unsigned long long u64_t;
typedef __attribute__((ext_vector_type(8))) short bf16x8;
typedef __attribute__((ext_vector_type(4))) float f32x4;
typedef __attribute__((ext_vector_type(4))) uint_t u32x4;

#define T_STEPS 1024
#define HID     512
#define KDIM    544   // 512 h + 32 x
#define NBLK    64    // 4 groups * 16 slices
#define NTHR    512

__device__ inline ushort_t f2bf(float x) {
    __hip_bfloat16 h = __float2bfloat16(x);
    return *(ushort_t*)&h;
}
__device__ inline float bf2f(ushort_t u) {
    __hip_bfloat16 h = *(__hip_bfloat16*)&u;
    return __bfloat162float(h);
}

__device__ inline f32x4 MFMA(bf16x8 a, bf16x8 b, f32x4 c) {
    return __builtin_amdgcn_mfma_f32_16x16x32_bf16(a, b, c, 0, 0, 0);
}

// coherent 16B load / 4B store (L1+L2 bypass, meets at Infinity Cache)
__device__ inline u32x4 cld16(const void* p) {
    u32x4 v;
    asm volatile("global_load_dwordx4 %0, %1, off sc0 sc1"
                 : "=v"(v) : "v"(p) : "memory");
    return v;
}
__device__ inline void cst4(void* p, uint_t v) {
    asm volatile("global_store_dword %0, %1, off sc0 sc1"
                 :: "v"(p), "v"(v) : "memory");
}
__device__ inline void waitvm0() {
    asm volatile("s_waitcnt vmcnt(0)" ::: "memory");
}

// is_tanh: tanh(v)=(1-e)/(1+e), e=2^(-2.885*v); sigmoid(v)=1/(1+e), e=2^(-1.4427*v)
__device__ inline float act_gate(float v, int is_tanh) {
    float vc = fminf(fmaxf(v, -43.f), 43.f);
    float kk = is_tanh ? -2.88539008f : -1.44269504f;
    float e  = __builtin_exp2f(vc * kk);
    float num = is_tanh ? (1.f - e) : 1.f;
    return num * __builtin_amdgcn_rcpf(1.f + e);
}

// ---------- prep kernels ----------

__global__ void k_init(uint_t* hx32) {
    int i = blockIdx.x * 256 + threadIdx.x;      // grid 256x256 = 65536
    // init h ring: value ~0 (denormal bf16), tag bit16 = 1 (differs from tag 0
    // expected at t=1/t=2) -> no ABA with init data.
    hx32[i] = 0x00010000u;                       // 2*4*128*16 x 16B = 65536 u32
}

__global__ void k_wcat(const float* __restrict__ wih, const float* __restrict__ whh,
                       ushort_t* __restrict__ wh, ushort_t* __restrict__ wl) {
    int r = blockIdx.x;                          // 2048 gate rows
    for (int k = threadIdx.x; k < KDIM; k += 256) {
        float w = (k < 512) ? whh[r * 512 + k] : wih[r * 32 + (k - 512)];
        ushort_t hh = f2bf(w);
        ushort_t ll = f2bf(w - bf2f(hh));
        wh[r * KDIM + k] = hh;
        wl[r * KDIM + k] = ll;
    }
}

// input (B=64, D=32, T=1024) fp32 -> xbuf[t][b][d] bf16 hi/lo
__global__ void k_xbuf(const float* __restrict__ in,
                       ushort_t* __restrict__ xh, ushort_t* __restrict__ xl) {
    __shared__ float tile[64][65];
    int bp = blockIdx.x >> 4;                    // batch pair 0..31
    int tt = blockIdx.x & 15;                    // t tile 0..15
    int t0 = tt * 64;
    int wv = threadIdx.x >> 6, l = threadIdx.x & 63;
    for (int r = wv * 16; r < wv * 16 + 16; r++) {
        int b = bp * 2 + (r >> 5), d = r & 31;
        tile[r][l] = in[(b * 32 + d) * 1024 + t0 + l];
    }
    __syncthreads();
    for (int i = 0; i < 16; i++) {
        int tl = wv * 16 + i;
        float v = tile[l][tl];
        ushort_t hh = f2bf(v);
        ushort_t ll = f2bf(v - bf2f(hh));
        int o = (t0 + tl) * 2048 + bp * 64 + l;  // = t*64*32 + b*32 + d
        xh[o] = hh;
        xl[o] = ll;
    }
}

// out[b][t] = conv_b + sum_s part[(g*16+s)*16 + bl][t]   (b = g*16+bl)
__global__ void k_reduce(const float* __restrict__ part, float* __restrict__ out,
                         const float* __restrict__ cvb) {
    int b = blockIdx.x >> 2;                     // 0..63
    int t = (blockIdx.x & 3) * 256 + threadIdx.x;
    int g = b >> 4, bl = b & 15;
    const float* p = part + ((size_t)(g * 16 * 16 + bl)) * 1024 + t;
    float sum = 0.f;
    #pragma unroll
    for (int s = 0; s < 16; s++) sum += p[(size_t)s * 16 * 1024];
    out[b * 1024 + t] = sum + cvb[0];
}

// ---------- main recurrent kernel ----------

__global__ __launch_bounds__(NTHR, 2) void k_lstm(
    const ushort_t* __restrict__ wh, const ushort_t* __restrict__ wlo,
    const ushort_t* __restrict__ xh, const ushort_t* __restrict__ xl,
    char* hx,
    const float* __restrict__ bih, const float* __restrict__ bhh,
    const float* __restrict__ convw, float* __restrict__ part)
{
    const int tid = threadIdx.x;
    const int w   = tid >> 6;          // wave 0..7
    const int l   = tid & 63;
    const int g   = blockIdx.x >> 4;   // batch group 0..3
    const int s   = blockIdx.x & 15;   // hidden slice 0..15 (32 units each)
    const int n   = l & 15;            // A-tile row (u-major: u=n>>2, gate=n&3)
    const int q   = l >> 4;            // quad (k-block; also: unit in epilogue)
    const int j   = s * 32 + w * 4 + q;// hidden unit owned in epilogue
    // weight row for the A-operand, tile rows ordered unit-major:
    // tile-row n -> global row = (n&3)*HID + s*32 + w*4 + (n>>2)
    const int roww = (n & 3) * HID + s * 32 + w * 4 + (n >> 2);
    const int b0  = g * 16;
    const int wg  = s * 8 + w;         // producing-wave id in group, 0..127

    __shared__ u64_t hs[2][2048];              // staged h_hi, dbuf (32 KB)
    __shared__ float projsh[8][16][32];        // projection partials (16 KB)

    // W_hi AND W_lo fragments in registers: 17 K-chunks each (A-operand)
    bf16x8 Bh[17], Bl[17];
    #pragma unroll
    for (int c = 0; c < 17; c++) {
        Bh[c] = *(const bf16x8*)(wh  + roww * KDIM + c * 32 + q * 8);
        Bl[c] = *(const bf16x8*)(wlo + roww * KDIM + c * 32 + q * 8);
    }

    // epilogue constants: lane (q,n) owns unit j, batch n -> 4 gate biases
    float bias4[4];
    #pragma unroll
    for (int r = 0; r < 4; r++) bias4[r] = bih[r * HID + j] + bhh[r * HID + j];
    const float cw = convw[j];
    float cst = 0.f;                   // c-state: one (unit, batch) per lane

    // staging mapping: packet p = k*512+tid (k=0..3) -> wg' = p>>4, m = p&15
    // c = k*4 + (hi5>>3), sq = (hi5>>1)&3, sd = hi5&1
    const int m16 = tid & 15;
    const int hi5 = tid >> 4;
    const int sq  = (hi5 >> 1) & 3, sd = hi5 & 1, sc0v = hi5 >> 3;

    __syncthreads();

    union frag { u64_t d[2]; bf16x8 v; };

    for (int t = 0; t < T_STEPS; t++) {
        bf16x8 Ax, Lx;
        // x fragment (B-operand: lane (q,n) = x[batch n][dims q*8..+8])
        {
            int xo = (t * 64 + b0 + n) * 32 + q * 8;
            Ax = *(const bf16x8*)(xh + xo);
            Lx = *(const bf16x8*)(xl + xo);
        }

        // ---- stage + poll-on-data: 4 coherent 16B loads, tag every word ----
        const char* srcB = hx + (size_t)(((t & 1) * 4 + g)) * 32768 + tid * 16;
        u32x4 hv[4];
        #pragma unroll
        for (int k = 0; k < 4; k++) hv[k] = cld16(srcB + k * 8192);
        waitvm0();
        if (t > 0) {
            const uint_t exp = ((uint_t)(((t - 1) >> 1) & 1)) << 16;
            for (;;) {
                bool ok = true;
                #pragma unroll
                for (int k = 0; k < 4; k++) {
                    if (((hv[k][0] & 0x10000u) != exp) ||
                        ((hv[k][1] & 0x10000u) != exp) ||
                        ((hv[k][2] & 0x10000u) != exp) ||
                        ((hv[k][3] & 0x10000u) != exp)) {
                        hv[k] = cld16(srcB + k * 8192);
                        ok = false;
                    }
                }
                if (ok) break;
                __builtin_amdgcn_s_sleep(1);   // backoff: decongest fabric
                waitvm0();
            }
        }
        // deinterleave: keep only the hi half of each (hi,lo) word; into LDS
        {
            const int buf = t & 1;
            #pragma unroll
            for (int k = 0; k < 4; k++) {
                uint_t I0 = hv[k][0], I1 = hv[k][1];
                uint_t I2 = hv[k][2], I3 = hv[k][3];
                uint_t hA = __builtin_amdgcn_perm(I1, I0, 0x05040100u);
                uint_t hB = __builtin_amdgcn_perm(I3, I2, 0x05040100u);
                int c  = k * 4 + sc0v;
                int li = ((c * 4 + sq) * 16 + m16) * 2 + sd;
                hs[buf][li] = (u64_t)hA | ((u64_t)hB << 32);
            }
        }
        __syncthreads();   // the only per-step barrier

        // fragments from LDS (B-operand, hi plane only); W in VGPRs (A-op).
        // 1 ds_read_b128 + 2 MFMAs per chunk (LDS-pipe/matrix-pipe balanced).
        const int buf = t & 1;
        f32x4 a0 = {0,0,0,0}, a1 = {0,0,0,0}, a2 = {0,0,0,0},
              a3 = {0,0,0,0};
        #pragma unroll
        for (int c = 0; c < 16; c++) {
            frag Ah;
            int li = ((c * 4 + q) * 16 + n) * 2;
            Ah.v = *(const bf16x8*)&hs[buf][li];
            if (c & 1) {
                a1 = MFMA(Bh[c], Ah.v, a1);
                a3 = MFMA(Bl[c], Ah.v, a3);
            } else {
                a0 = MFMA(Bh[c], Ah.v, a0);
                a2 = MFMA(Bl[c], Ah.v, a2);
            }
        }
        {   // x chunk (c=16): keep full hi/lo for x (1 extra MFMA only)
            a0 = MFMA(Bh[16], Ax, a0);
            a2 = MFMA(Bl[16], Ax, a2);
            a1 = MFMA(Bh[16], Lx, a1);
        }
        f32x4 D = (a0 + a1) + (a2 + a3);

        // ---- lane-local epilogue: D[r] = gate r of (unit j, batch n) ----
        char* dstB = hx + (size_t)((((t + 1) & 1) * 4 + g) * 128 + wg) * 256;
        const uint_t tag32 = ((uint_t)((t >> 1) & 1)) << 16;
        float iv = act_gate(D[0] + bias4[0], 0);
        float fv = act_gate(D[1] + bias4[1], 0);
        float gv = act_gate(D[2] + bias4[2], 1);
        float ov = act_gate(D[3] + bias4[3], 0);
        float cc = fv * cst + iv * gv;
        cst = cc;
        float th = act_gate(cc, 1);
        float h  = ov * th;
        float pr = cw * h;
        {
            ushort_t hb = f2bf(h);
            uint_t hvp = (uint_t)hb;
            uint_t lvp = (uint_t)f2bf(h - bf2f(hb));
            uint_t word = (hvp | (lvp << 16)) & ~0x10000u;
            word |= tag32;                       // every word self-tagged
            // packet layout: wg*256 + batch*16 + unit*4 (identical to R13)
            cst4(dstB + n * 16 + q * 4, word);
        }
        // NO drain, NO flag: tagged data IS the publication.

        // projection partial (off critical path): sum over the wave's 4 units
        pr += __shfl_xor(pr, 16);
        pr += __shfl_xor(pr, 32);
        if (l < 16) projsh[w][l][t & 31] = pr;   // l==n when q==0
        if ((t & 31) == 31) {
            __syncthreads();
            // 512 entries (16 batches x 32 steps), one per thread
            int b = tid >> 5, tl = tid & 31;
            float v = ((projsh[0][b][tl] + projsh[1][b][tl]) +
                       (projsh[2][b][tl] + projsh[3][b][tl])) +
                      ((projsh[4][b][tl] + projsh[5][b][tl]) +
                       (projsh[6][b][tl] + projsh[7][b][tl]));
            float* dpt = part + (size_t)((g * 16 + s) * 16 + b) * 1024 + (t - 31);
            __builtin_nontemporal_store(v, dpt + tl);
            __syncthreads();
        }
    }
}

extern "C" void kernel_launch(void* const* d_in, const int* in_sizes, int n_in,
                              void* d_out, int out_size, void* d_ws, size_t ws_size,
                              hipStream_t stream) {
    const float* in  = (const float*)d_in[0];
    const float* Wih = (const float*)d_in[1];
    const float* Whh = (const float*)d_in[2];
    const float* bih = (const float*)d_in[3];
    const float* bhh = (const float*)d_in[4];
    const float* cvw = (const float*)d_in[5];
    const float* cvb = (const float*)d_in[6];
    float* out = (float*)d_out;

    char* ws = (char*)d_ws;
    ushort_t* wh  = (ushort_t*)ws; ws += (size_t)2048 * KDIM * 2;      // 2,228,224
    ushort_t* wl  = (ushort_t*)ws; ws += (size_t)2048 * KDIM * 2;
    ushort_t* xh  = (ushort_t*)ws; ws += (size_t)1024 * 64 * 32 * 2;   // 4,194,304
    ushort_t* xl  = (ushort_t*)ws; ws += (size_t)1024 * 64 * 32 * 2;
    char*     hx  = ws;            ws += (size_t)2 * 4 * 128 * 16 * 16;// 262,144
    float*    pp  = (float*)ws;    ws += (size_t)64 * 16 * 1024 * 4;   // 4,194,304
    // total ~17.3 MB of ws

    k_init<<<256, 256, 0, stream>>>((uint_t*)hx);
    k_wcat<<<2048, 256, 0, stream>>>(Wih, Whh, wh, wl);
    k_xbuf<<<512, 256, 0, stream>>>(in, xh, xl);
    k_lstm<<<NBLK, NTHR, 0, stream>>>(wh, wl, xh, xl, hx,
                                      bih, bhh, cvw, pp);
    k_reduce<<<256, 256, 0, stream>>>(pp, out, cvb);
}